// Round 1
// baseline (808.927 us; speedup 1.0000x reference)
//
#include <hip/hip_runtime.h>
#include <math.h>

// TSMixerH: B=32,C=256,L=336,O=96,K=4,NL=2,DFF=1024
// Round 1: correct fp32 register-blocked implementation.
//   - rows grouped by cluster (each row computed ONLY with its assigned
//     cluster -> 4x fewer FLOPs than the reference's compute-all-and-select)
//   - 512 tiles of 16 rows each (32*cnt_k always divisible by 16 -> exact,
//     fixed grid, graph-capture safe)
//   - fused RevIN + 2 residual MLP layers + head + denorm + transpose

constexpr int B = 32, C = 256, L = 336, O = 96, K = 4, NL = 2, DFF = 1024;
constexpr int TM = 16;                   // rows per tile
constexpr int NTILES = (B * C) / TM;     // 512 (exact)
constexpr int DC = 256;                  // DFF chunk
constexpr int ZSTRIDE = 344;             // 336 + 8 pad (16B-aligned rows)
constexpr int HSTRIDE = DC + 8;          // 264 (16B-aligned rows)

// meta layout (ints): [0..511] tiles (k<<16 | row_start),
//                     [512..767] chlist (channels grouped by cluster),
//                     [768..772] cofs (cluster offsets, K+1)
__global__ void build_tables(const int* __restrict__ assign,
                             int* __restrict__ meta) {
  if (threadIdx.x == 0 && blockIdx.x == 0) {
    int cnt[K] = {0, 0, 0, 0};
    for (int c = 0; c < C; ++c) cnt[assign[c]]++;
    int cofs[K + 1];
    cofs[0] = 0;
    for (int k = 0; k < K; ++k) cofs[k + 1] = cofs[k] + cnt[k];
    for (int k = 0; k <= K; ++k) meta[768 + k] = cofs[k];
    int pos[K];
    for (int k = 0; k < K; ++k) pos[k] = cofs[k];
    for (int c = 0; c < C; ++c) meta[512 + pos[assign[c]]++] = c;
    int t = 0;
    for (int k = 0; k < K; ++k)
      for (int s = 0; s < 32 * cnt[k]; s += TM) meta[t++] = (k << 16) | s;
    // t == 512 always (sum cnt_k == 256)
  }
}

__global__ __launch_bounds__(256) void mlp_fused(
    const float* __restrict__ x, const float* __restrict__ rev_w,
    const float* __restrict__ rev_b, const float* __restrict__ W1,
    const float* __restrict__ b1, const float* __restrict__ W2,
    const float* __restrict__ b2, const float* __restrict__ Wh,
    const float* __restrict__ bh, const int* __restrict__ meta,
    float* __restrict__ out) {
  __shared__ __align__(16) float zsh[TM][ZSTRIDE];
  __shared__ __align__(16) float hsh[TM][HSTRIDE];
  __shared__ float s_mean[TM], s_std[TM], s_rw[TM], s_rb[TM];
  __shared__ int s_b[TM], s_c[TM];

  const int tid = threadIdx.x;
  const int wid = tid >> 6;   // wave id 0..3
  const int lane = tid & 63;

  const int info = meta[blockIdx.x];
  const int k = info >> 16;
  const int rstart = info & 0xffff;  // row start within this cluster's rows
  const int cofs_k = meta[768 + k];
  const int cnt = meta[768 + k + 1] - cofs_k;  // >=1 for any existing tile

  // ---- load 16 rows, compute RevIN stats, write normalized z to LDS ----
  for (int i = 0; i < 4; ++i) {
    const int t = wid * 4 + i;
    const int ri = rstart + t;
    const int b = ri / cnt;
    const int c = meta[512 + cofs_k + (ri % cnt)];
    const float* xrow = x + (size_t)(b * C + c) * L;
    float v[6], s = 0.f, s2 = 0.f;
#pragma unroll
    for (int jj = 0; jj < 6; ++jj) {
      const int j = lane + jj * 64;
      v[jj] = (j < L) ? xrow[j] : 0.f;
      s += v[jj];
      s2 += v[jj] * v[jj];
    }
#pragma unroll
    for (int off = 32; off > 0; off >>= 1) {
      s += __shfl_down(s, off);
      s2 += __shfl_down(s2, off);
    }
    s = __shfl(s, 0);
    s2 = __shfl(s2, 0);
    const float mean = s * (1.f / L);
    const float var = s2 * (1.f / L) - mean * mean;
    const float stdv = sqrtf(var + 1e-5f);
    const float rstd = 1.f / stdv;
    const float rw = rev_w[c], rb_ = rev_b[c];
#pragma unroll
    for (int jj = 0; jj < 6; ++jj) {
      const int j = lane + jj * 64;
      if (j < L) zsh[t][j] = (v[jj] - mean) * rstd * rw + rb_;
    }
    if (lane == 0) {
      s_mean[t] = mean;
      s_std[t] = stdv;
      s_rw[t] = rw;
      s_rb[t] = rb_;
      s_b[t] = b;
      s_c[t] = c;
    }
  }
  __syncthreads();

  // ---- 2 residual MLP layers ----
  for (int l = 0; l < NL; ++l) {
    const float* W1p = W1 + (size_t)(k * NL + l) * L * DFF;
    const float* b1p = b1 + (k * NL + l) * DFF;
    const float* W2p = W2 + (size_t)(k * NL + l) * DFF * L;
    const float* b2p = b2 + (k * NL + l) * L;

    // persistent accumulators for z update: rows wid+4*rb, cols lane+64*lb
    float zacc[4][6];
#pragma unroll
    for (int rb = 0; rb < 4; ++rb)
#pragma unroll
      for (int lb = 0; lb < 6; ++lb) zacc[rb][lb] = 0.f;

    for (int cc = 0; cc < DFF / DC; ++cc) {
      const int d0 = cc * DC;

      // -- phase 1: H[r][d0+lane*4 .. +3] = relu(z @ W1 + b1), 4 rows/thread
      {
        float4 hv[4];
#pragma unroll
        for (int rb = 0; rb < 4; ++rb) hv[rb] = make_float4(0.f, 0.f, 0.f, 0.f);
        const float* W1c = W1p + d0 + lane * 4;
        for (int j = 0; j < L; j += 4) {
          const float4 w0 = *(const float4*)(W1c + (size_t)(j + 0) * DFF);
          const float4 w1 = *(const float4*)(W1c + (size_t)(j + 1) * DFF);
          const float4 w2 = *(const float4*)(W1c + (size_t)(j + 2) * DFF);
          const float4 w3 = *(const float4*)(W1c + (size_t)(j + 3) * DFF);
#pragma unroll
          for (int rb = 0; rb < 4; ++rb) {
            const int r = wid + 4 * rb;
            const float4 zq = *(const float4*)&zsh[r][j];
            hv[rb].x += zq.x * w0.x + zq.y * w1.x + zq.z * w2.x + zq.w * w3.x;
            hv[rb].y += zq.x * w0.y + zq.y * w1.y + zq.z * w2.y + zq.w * w3.y;
            hv[rb].z += zq.x * w0.z + zq.y * w1.z + zq.z * w2.z + zq.w * w3.z;
            hv[rb].w += zq.x * w0.w + zq.y * w1.w + zq.z * w2.w + zq.w * w3.w;
          }
        }
        const float4 bq = *(const float4*)(b1p + d0 + lane * 4);
#pragma unroll
        for (int rb = 0; rb < 4; ++rb) {
          const int r = wid + 4 * rb;
          float4 hh;
          hh.x = fmaxf(hv[rb].x + bq.x, 0.f);
          hh.y = fmaxf(hv[rb].y + bq.y, 0.f);
          hh.z = fmaxf(hv[rb].z + bq.z, 0.f);
          hh.w = fmaxf(hv[rb].w + bq.w, 0.f);
          *(float4*)&hsh[r][lane * 4] = hh;
        }
      }
      __syncthreads();

      // -- phase 2: zacc[r][l] += H_chunk @ W2[d0:d0+DC, :]
      for (int dd = 0; dd < DC; dd += 4) {
        float4 hq[4];
#pragma unroll
        for (int rb = 0; rb < 4; ++rb)
          hq[rb] = *(const float4*)&hsh[wid + 4 * rb][dd];
        const float* W2r = W2p + (size_t)(d0 + dd) * L;
#pragma unroll
        for (int lb = 0; lb < 6; ++lb) {
          const int lcol = lane + 64 * lb;
          if (lcol < L) {
            const float w20 = W2r[lcol];
            const float w21 = W2r[L + lcol];
            const float w22 = W2r[2 * L + lcol];
            const float w23 = W2r[3 * L + lcol];
#pragma unroll
            for (int rb = 0; rb < 4; ++rb) {
              zacc[rb][lb] += hq[rb].x * w20 + hq[rb].y * w21 +
                              hq[rb].z * w22 + hq[rb].w * w23;
            }
          }
        }
      }
      __syncthreads();  // hsh reads done before next chunk overwrites
    }

    // -- z update: z += H@W2 + b2
#pragma unroll
    for (int lb = 0; lb < 6; ++lb) {
      const int lcol = lane + 64 * lb;
      if (lcol < L) {
        const float bb = b2p[lcol];
#pragma unroll
        for (int rb = 0; rb < 4; ++rb) {
          const int r = wid + 4 * rb;
          zsh[r][lcol] += zacc[rb][lb] + bb;
        }
      }
    }
    __syncthreads();
  }

  // ---- head: y = z @ Wh + bh, denorm, write out[b][o][c] ----
  const float* Whp = Wh + (size_t)k * L * O;
  const float* bhp = bh + k * O;
#pragma unroll
  for (int ob = 0; ob < 2; ++ob) {
    const int o = lane + 64 * ob;
    if (o < O) {
      float acc[4] = {0.f, 0.f, 0.f, 0.f};
      for (int j = 0; j < L; ++j) {
        const float w = Whp[j * O + o];
#pragma unroll
        for (int rb = 0; rb < 4; ++rb) acc[rb] += zsh[wid + 4 * rb][j] * w;
      }
#pragma unroll
      for (int rb = 0; rb < 4; ++rb) {
        const int t = wid + 4 * rb;
        const float y = acc[rb] + bhp[o];
        const float dn = (y - s_rb[t]) / s_rw[t] * s_std[t] + s_mean[t];
        out[((size_t)s_b[t] * O + o) * C + s_c[t]] = dn;
      }
    }
  }
}

extern "C" void kernel_launch(void* const* d_in, const int* in_sizes, int n_in,
                              void* d_out, int out_size, void* d_ws,
                              size_t ws_size, hipStream_t stream) {
  const float* x = (const float*)d_in[0];
  const float* rev_w = (const float*)d_in[1];
  const float* rev_b = (const float*)d_in[2];
  const float* W1 = (const float*)d_in[3];
  const float* b1 = (const float*)d_in[4];
  const float* W2 = (const float*)d_in[5];
  const float* b2 = (const float*)d_in[6];
  const float* Wh = (const float*)d_in[7];
  const float* bh = (const float*)d_in[8];
  const int* assign = (const int*)d_in[9];
  float* out = (float*)d_out;
  int* meta = (int*)d_ws;  // needs ~3.1 KB

  build_tables<<<1, 64, 0, stream>>>(assign, meta);
  mlp_fused<<<NTILES, 256, 0, stream>>>(x, rev_w, rev_b, W1, b1, W2, b2, Wh,
                                        bh, meta, out);
}

// Round 3
// 209.753 us; speedup vs baseline: 3.8566x; 3.8566x over previous
//
#include <hip/hip_runtime.h>
#include <math.h>

// TSMixerH: B=32,C=256,L=336,O=96,K=4,NL=2,DFF=1024
// Round 3: bf16 MFMA (16x16x32), fixing round-2's fragment-offset bug:
//   tile nt's fragments live at element offset nt*KS*512 (64 lanes x 8 u16),
//   round 2 used nt*KS*64 (forgot the x8) -> all nt>0 tiles read garbage.
//   - repack kernel: W1/W2/Wh -> bf16 MFMA A-fragment layout in d_ws
//   - swapped operands: D[m=feature][n=row] = W^T-frag (A) x z/H-frag (B)
//   - fp32 residual master z32 in LDS; bf16 only at MFMA inputs

typedef unsigned short u16;
typedef unsigned int u32;

constexpr int B = 32, C = 256, L = 336, O = 96, K = 4, NL = 2, DFF = 1024;
constexpr int TM = 16;
constexpr int NTILES = (B * C) / TM;  // 512
constexpr int LP = 352;               // L padded to mult of 32
constexpr int KS1 = LP / 32;          // 11  (K-steps over L)
constexpr int NT1 = DFF / 16;         // 64  (d-tiles, phase 1)
constexpr int KS2 = DFF / 32;         // 32  (K-steps over DFF)
constexpr int NT2 = LP / 16;          // 22  (l-tiles, phase 2)
constexpr int NTH = O / 16;           // 6   (o-tiles, head)
constexpr int Z32S = 356;             // fp32 z row stride
constexpr int ZBS = 360;              // bf16 z row stride
constexpr int HS = 1032;              // bf16 H row stride

constexpr int W1FRAGS = NT1 * KS1 * 64;  // 45056 lane-frags per (k,layer)
constexpr int W2FRAGS = NT2 * KS2 * 64;  // 45056
constexpr int WHFRAGS = NTH * KS1 * 64;  // 4224
constexpr int NW1 = W1FRAGS * K * NL;    // 360448
constexpr int NW2 = W2FRAGS * K * NL;    // 360448
constexpr int NWH = WHFRAGS * K;         // 16896
constexpr int NFRAG = NW1 + NW2 + NWH;   // 737792 (= 2882 * 256 exactly)

typedef __bf16 bf16x8 __attribute__((ext_vector_type(8)));
typedef float f32x4 __attribute__((ext_vector_type(4)));

__device__ __forceinline__ u16 f2bf(float f) {
  union { float f; u32 u; } v;
  v.f = f;
  u32 r = v.u + 0x7fffu + ((v.u >> 16) & 1u);  // RNE
  return (u16)(r >> 16);
}

// meta layout (ints): [0..511] tiles (k<<16 | row_start),
//                     [512..767] chlist, [768..772] cluster offsets
__global__ void build_tables(const int* __restrict__ assign,
                             int* __restrict__ meta) {
  if (threadIdx.x == 0 && blockIdx.x == 0) {
    int cnt[K] = {0, 0, 0, 0};
    for (int c = 0; c < C; ++c) cnt[assign[c]]++;
    int cofs[K + 1];
    cofs[0] = 0;
    for (int k = 0; k < K; ++k) cofs[k + 1] = cofs[k] + cnt[k];
    for (int k = 0; k <= K; ++k) meta[768 + k] = cofs[k];
    int pos[K];
    for (int k = 0; k < K; ++k) pos[k] = cofs[k];
    for (int c = 0; c < C; ++c) meta[512 + pos[assign[c]]++] = c;
    int t = 0;
    for (int k = 0; k < K; ++k)
      for (int s = 0; s < 32 * cnt[k]; s += TM) meta[t++] = (k << 16) | s;
  }
}

// Repack weights into bf16 A-fragment order.
// A-fragment (16x16x32): lane holds A[m=lane&15][k=(lane>>4)*8+j], j=0..7.
// W1 (phase 1, A = W1^T): m=d, k=l.  W2 (phase 2, A = W2^T): m=l, k=d.
// Wh (head, A = Wh^T): m=o, k=l.  Pad k/m beyond L with zeros.
__global__ __launch_bounds__(256) void repack(const float* __restrict__ W1,
                                              const float* __restrict__ W2,
                                              const float* __restrict__ Wh,
                                              u16* __restrict__ wbuf) {
  const int gid = blockIdx.x * 256 + threadIdx.x;
  const int lane = gid & 63;
  const int q = lane >> 4, rm = lane & 15;
  float v[8];
  if (gid < NW1) {
    const int kl = gid / W1FRAGS, rem = gid % W1FRAGS;
    const int nt = rem / (KS1 * 64), ks = (rem / 64) % KS1;
    const int d = nt * 16 + rm, lb = ks * 32 + q * 8;
    const float* src = W1 + (size_t)kl * L * DFF;
#pragma unroll
    for (int j = 0; j < 8; ++j) {
      const int l = lb + j;
      v[j] = (l < L) ? src[(size_t)l * DFF + d] : 0.f;
    }
  } else if (gid < NW1 + NW2) {
    const int g = gid - NW1;
    const int kl = g / W2FRAGS, rem = g % W2FRAGS;
    const int nt = rem / (KS2 * 64), ks = (rem / 64) % KS2;
    const int lcol = nt * 16 + rm, db = ks * 32 + q * 8;
    const float* src = W2 + (size_t)kl * DFF * L;
#pragma unroll
    for (int j = 0; j < 8; ++j)
      v[j] = (lcol < L) ? src[(size_t)(db + j) * L + lcol] : 0.f;
  } else {
    const int g = gid - NW1 - NW2;
    const int kk = g / WHFRAGS, rem = g % WHFRAGS;
    const int nt = rem / (KS1 * 64), ks = (rem / 64) % KS1;
    const int o = nt * 16 + rm, lb = ks * 32 + q * 8;
    const float* src = Wh + (size_t)kk * L * O;
#pragma unroll
    for (int j = 0; j < 8; ++j) {
      const int l = lb + j;
      v[j] = (l < L) ? src[(size_t)l * O + o] : 0.f;
    }
  }
  uint4 w;
  w.x = (u32)f2bf(v[0]) | ((u32)f2bf(v[1]) << 16);
  w.y = (u32)f2bf(v[2]) | ((u32)f2bf(v[3]) << 16);
  w.z = (u32)f2bf(v[4]) | ((u32)f2bf(v[5]) << 16);
  w.w = (u32)f2bf(v[6]) | ((u32)f2bf(v[7]) << 16);
  *(uint4*)(wbuf + (size_t)gid * 8) = w;
}

__global__ __launch_bounds__(256) void mlp_mfma(
    const float* __restrict__ x, const float* __restrict__ rev_w,
    const float* __restrict__ rev_b, const float* __restrict__ b1,
    const float* __restrict__ b2, const float* __restrict__ bh,
    const int* __restrict__ meta, const u16* __restrict__ wbuf,
    float* __restrict__ out) {
  __shared__ __align__(16) float z32[TM][Z32S];   // fp32 residual master
  __shared__ __align__(16) u16 zb[TM][ZBS];       // bf16 z (B-frag source)
  __shared__ __align__(16) u16 Hsh[TM][HS];       // bf16 H (B-frag source)
  __shared__ float s_mean[TM], s_std[TM], s_rw[TM], s_rb[TM];
  __shared__ int s_b[TM], s_c[TM];

  const int tid = threadIdx.x;
  const int wid = tid >> 6;
  const int lane = tid & 63;
  const int q = lane >> 4, rm = lane & 15;

  const int info = meta[blockIdx.x];
  const int kcl = info >> 16;
  const int rstart = info & 0xffff;
  const int cofs = meta[768 + kcl];
  const int cnt = meta[768 + kcl + 1] - cofs;

  // ---- RevIN: load 16 rows, stats, write z32 + zb (normalized) ----
  for (int i = 0; i < 4; ++i) {
    const int t = wid * 4 + i;
    const int ri = rstart + t;
    const int b = ri / cnt;
    const int c = meta[512 + cofs + (ri % cnt)];
    const float* xrow = x + (size_t)(b * C + c) * L;
    float v[6], s = 0.f, s2 = 0.f;
#pragma unroll
    for (int jj = 0; jj < 6; ++jj) {
      const int j = lane + jj * 64;
      v[jj] = (j < L) ? xrow[j] : 0.f;
      s += v[jj];
      s2 += v[jj] * v[jj];
    }
#pragma unroll
    for (int off = 32; off > 0; off >>= 1) {
      s += __shfl_down(s, off);
      s2 += __shfl_down(s2, off);
    }
    s = __shfl(s, 0);
    s2 = __shfl(s2, 0);
    const float mean = s * (1.f / L);
    const float var = s2 * (1.f / L) - mean * mean;
    const float stdv = sqrtf(var + 1e-5f);
    const float rstd = 1.f / stdv;
    const float rw = rev_w[c], rb_ = rev_b[c];
#pragma unroll
    for (int jj = 0; jj < 6; ++jj) {
      const int j = lane + jj * 64;
      if (j < L) {
        const float zn = (v[jj] - mean) * rstd * rw + rb_;
        z32[t][j] = zn;
        zb[t][j] = f2bf(zn);
      }
    }
    if (lane < LP - L) {  // zero K-padding cols 336..351
      z32[t][L + lane] = 0.f;
      zb[t][L + lane] = 0;
    }
    if (lane == 0) {
      s_mean[t] = mean;
      s_std[t] = stdv;
      s_rw[t] = rw;
      s_rb[t] = rb_;
      s_b[t] = b;
      s_c[t] = c;
    }
  }
  __syncthreads();

  const u16* w1b = wbuf;
  const u16* w2b = wbuf + (size_t)NW1 * 8;
  const u16* whb = wbuf + (size_t)(NW1 + NW2) * 8;

  // ---- 2 residual MLP layers ----
  for (int l = 0; l < NL; ++l) {
    const int kl = kcl * NL + l;
    const u16* W1f = w1b + (size_t)kl * W1FRAGS * 8;
    const u16* W2f = w2b + (size_t)kl * W2FRAGS * 8;
    const float* b1p = b1 + kl * DFF;
    const float* b2p = b2 + kl * L;

    // z B-fragments: B[k=32ks+q*8+j][n=rm] = zb[rm][32ks+q*8+j]
    bf16x8 zf[KS1];
#pragma unroll
    for (int ks = 0; ks < KS1; ++ks)
      zf[ks] = *(const bf16x8*)&zb[rm][ks * 32 + q * 8];

    // phase 1: H^T tiles. D[m=d=16nt+q*4+reg][n=row=rm]
    for (int t = 0; t < 16; ++t) {
      const int nt = wid * 16 + t;
      const u16* wp = W1f + ((size_t)nt * (KS1 * 512) + lane * 8);
      f32x4 acc = {0.f, 0.f, 0.f, 0.f};
#pragma unroll
      for (int ks = 0; ks < KS1; ++ks) {
        const bf16x8 af = *(const bf16x8*)(wp + (size_t)ks * 512);
        acc = __builtin_amdgcn_mfma_f32_16x16x32_bf16(af, zf[ks], acc, 0, 0, 0);
      }
      const float4 bq = *(const float4*)(b1p + nt * 16 + q * 4);
      const u16 h0 = f2bf(fmaxf(acc[0] + bq.x, 0.f));
      const u16 h1 = f2bf(fmaxf(acc[1] + bq.y, 0.f));
      const u16 h2 = f2bf(fmaxf(acc[2] + bq.z, 0.f));
      const u16 h3 = f2bf(fmaxf(acc[3] + bq.w, 0.f));
      uint2 hw;
      hw.x = (u32)h0 | ((u32)h1 << 16);
      hw.y = (u32)h2 | ((u32)h3 << 16);
      *(uint2*)&Hsh[rm][nt * 16 + q * 4] = hw;  // H row-major: H[row][d]
    }
    __syncthreads();

    // phase 2: z += H @ W2 + b2. D[m=l=16nt+q*4+reg][n=row=rm]
    for (int nt = wid; nt < NT2; nt += 4) {
      const u16* wp = W2f + ((size_t)nt * (KS2 * 512) + lane * 8);
      f32x4 acc = {0.f, 0.f, 0.f, 0.f};
#pragma unroll 8
      for (int ks = 0; ks < KS2; ++ks) {
        const bf16x8 af = *(const bf16x8*)(wp + (size_t)ks * 512);
        const bf16x8 hf = *(const bf16x8*)&Hsh[rm][ks * 32 + q * 8];
        acc = __builtin_amdgcn_mfma_f32_16x16x32_bf16(af, hf, acc, 0, 0, 0);
      }
      const int lc = nt * 16 + q * 4;
      float4 bq = make_float4(0.f, 0.f, 0.f, 0.f);
      if (lc < L) bq = *(const float4*)(b2p + lc);  // nt==21 tile is all pad
      float4 zq = *(const float4*)&z32[rm][lc];
      zq.x += acc[0] + bq.x;
      zq.y += acc[1] + bq.y;
      zq.z += acc[2] + bq.z;
      zq.w += acc[3] + bq.w;
      *(float4*)&z32[rm][lc] = zq;
      uint2 zw;
      zw.x = (u32)f2bf(zq.x) | ((u32)f2bf(zq.y) << 16);
      zw.y = (u32)f2bf(zq.z) | ((u32)f2bf(zq.w) << 16);
      *(uint2*)&zb[rm][lc] = zw;
    }
    __syncthreads();
  }

  // ---- head: y = z @ Wh + bh, denorm, scatter to out[b][o][c] ----
  {
    const u16* Whf = whb + (size_t)kcl * WHFRAGS * 8;
    bf16x8 zf[KS1];
#pragma unroll
    for (int ks = 0; ks < KS1; ++ks)
      zf[ks] = *(const bf16x8*)&zb[rm][ks * 32 + q * 8];
    const float mean = s_mean[rm], stdv = s_std[rm];
    const float rw = s_rw[rm], rb_ = s_rb[rm];
    const int ob = s_b[rm], oc = s_c[rm];
    for (int nt = wid; nt < NTH; nt += 4) {
      const u16* wp = Whf + ((size_t)nt * (KS1 * 512) + lane * 8);
      f32x4 acc = {0.f, 0.f, 0.f, 0.f};
#pragma unroll
      for (int ks = 0; ks < KS1; ++ks) {
        const bf16x8 af = *(const bf16x8*)(wp + (size_t)ks * 512);
        acc = __builtin_amdgcn_mfma_f32_16x16x32_bf16(af, zf[ks], acc, 0, 0, 0);
      }
      const float4 bq = *(const float4*)(bh + kcl * O + nt * 16 + q * 4);
      const float bqa[4] = {bq.x, bq.y, bq.z, bq.w};
#pragma unroll
      for (int g = 0; g < 4; ++g) {
        const int o = nt * 16 + q * 4 + g;
        const float y = acc[g] + bqa[g];
        const float dn = (y - rb_) / rw * stdv + mean;
        out[((size_t)ob * O + o) * C + oc] = dn;
      }
    }
  }
}

extern "C" void kernel_launch(void* const* d_in, const int* in_sizes, int n_in,
                              void* d_out, int out_size, void* d_ws,
                              size_t ws_size, hipStream_t stream) {
  const float* x = (const float*)d_in[0];
  const float* rev_w = (const float*)d_in[1];
  const float* rev_b = (const float*)d_in[2];
  const float* W1 = (const float*)d_in[3];
  const float* b1 = (const float*)d_in[4];
  const float* W2 = (const float*)d_in[5];
  const float* b2 = (const float*)d_in[6];
  const float* Wh = (const float*)d_in[7];
  const float* bh = (const float*)d_in[8];
  const int* assign = (const int*)d_in[9];
  float* out = (float*)d_out;

  int* meta = (int*)d_ws;                         // 3.1 KB
  u16* wbuf = (u16*)((char*)d_ws + 4096);         // 11.8 MB bf16 fragments

  build_tables<<<1, 64, 0, stream>>>(assign, meta);
  repack<<<NFRAG / 256, 256, 0, stream>>>(W1, W2, Wh, wbuf);
  mlp_mfma<<<NTILES, 256, 0, stream>>>(x, rev_w, rev_b, b1, b2, bh, meta, wbuf,
                                       out);
}

// Round 4
// 206.405 us; speedup vs baseline: 3.9191x; 1.0162x over previous
//
#include <hip/hip_runtime.h>
#include <math.h>

// TSMixerH: B=32,C=256,L=336,O=96,K=4,NL=2,DFF=1024
// Round 4: TM=32 row tiles (A-frag reuse x2 -> half L2 weight traffic),
//   parallel build_tables (r3's serial scratch-array version cost ~100us),
//   cluster->XCD affinity swizzle, fp32 residual master in registers.

typedef unsigned short u16;
typedef unsigned int u32;
typedef unsigned long long u64;

constexpr int B = 32, C = 256, L = 336, O = 96, K = 4, NL = 2, DFF = 1024;
constexpr int TM = 32;
constexpr int NTILES = (B * C) / TM;  // 256
constexpr int LP = 352;               // L padded to mult of 32
constexpr int KS1 = LP / 32;          // 11
constexpr int NT1 = DFF / 16;         // 64
constexpr int KS2 = DFF / 32;         // 32
constexpr int NT2 = LP / 16;          // 22
constexpr int NTH = O / 16;           // 6
constexpr int Z32S = 356;             // fp32 z row stride (16B-aligned rows)
constexpr int ZBS = 360;              // bf16 z row stride
constexpr int HSC = 1032;             // bf16 H row stride

constexpr int W1FRAGS = NT1 * KS1 * 64;  // 45056
constexpr int W2FRAGS = NT2 * KS2 * 64;  // 45056
constexpr int WHFRAGS = NTH * KS1 * 64;  // 4224
constexpr int NW1 = W1FRAGS * K * NL;    // 360448
constexpr int NW2 = W2FRAGS * K * NL;    // 360448
constexpr int NWH = WHFRAGS * K;         // 16896
constexpr int NFRAG = NW1 + NW2 + NWH;   // 737792 = 2882*256

typedef __bf16 bf16x8 __attribute__((ext_vector_type(8)));
typedef float f32x4 __attribute__((ext_vector_type(4)));

__device__ __forceinline__ u16 f2bf(float f) {
  union { float f; u32 u; } v;
  v.f = f;
  u32 r = v.u + 0x7fffu + ((v.u >> 16) & 1u);  // RNE
  return (u16)(r >> 16);
}

// meta layout (ints): [0..255] tiles (k<<16 | rstart-within-cluster),
//                     [256..511] chlist (channels grouped by cluster),
//                     [512..516] cofs
__global__ __launch_bounds__(256) void build_tables(
    const int* __restrict__ assign, int* __restrict__ meta) {
  __shared__ int wcnt[4][K];
  __shared__ int pre[4][K];
  __shared__ int cofs[K + 1];
  const int tid = threadIdx.x;
  const int w = tid >> 6, lane = tid & 63;
  const int a = assign[tid];
  const u64 below = (1ull << lane) - 1ull;
  int myrank = 0;
#pragma unroll
  for (int k = 0; k < K; ++k) {
    const u64 m = __ballot(a == k);
    if (a == k) myrank = (int)__popcll(m & below);
    if (lane == 0) wcnt[w][k] = (int)__popcll(m);
  }
  __syncthreads();
  if (tid == 0) {
    int tot[K];
    for (int k = 0; k < K; ++k) {
      int s = 0;
      for (int ww = 0; ww < 4; ++ww) {
        pre[ww][k] = s;
        s += wcnt[ww][k];
      }
      tot[k] = s;
    }
    cofs[0] = 0;
    for (int k = 0; k < K; ++k) cofs[k + 1] = cofs[k] + tot[k];
    for (int k = 0; k <= K; ++k) meta[512 + k] = cofs[k];
  }
  __syncthreads();
  const int pos = cofs[a] + pre[w][a] + myrank;
  meta[256 + pos] = tid;  // chlist
  // tile tid -> (cluster, rstart): cofs[k] <= tid < cofs[k+1]
  int k = 0;
  while (k < K - 1 && tid >= cofs[k + 1]) ++k;
  meta[tid] = (k << 16) | ((tid - cofs[k]) * TM);
}

// Repack weights into bf16 A-fragment order (unchanged from r3).
// A-frag (16x16x32): lane holds A[m=lane&15][k=(lane>>4)*8+j], j=0..7.
__global__ __launch_bounds__(256) void repack(const float* __restrict__ W1,
                                              const float* __restrict__ W2,
                                              const float* __restrict__ Wh,
                                              u16* __restrict__ wbuf) {
  const int gid = blockIdx.x * 256 + threadIdx.x;
  const int lane = gid & 63;
  const int q = lane >> 4, rm = lane & 15;
  float v[8];
  if (gid < NW1) {
    const int kl = gid / W1FRAGS, rem = gid % W1FRAGS;
    const int nt = rem / (KS1 * 64), ks = (rem / 64) % KS1;
    const int d = nt * 16 + rm, lb = ks * 32 + q * 8;
    const float* src = W1 + (size_t)kl * L * DFF;
#pragma unroll
    for (int j = 0; j < 8; ++j) {
      const int l = lb + j;
      v[j] = (l < L) ? src[(size_t)l * DFF + d] : 0.f;
    }
  } else if (gid < NW1 + NW2) {
    const int g = gid - NW1;
    const int kl = g / W2FRAGS, rem = g % W2FRAGS;
    const int nt = rem / (KS2 * 64), ks = (rem / 64) % KS2;
    const int lcol = nt * 16 + rm, db = ks * 32 + q * 8;
    const float* src = W2 + (size_t)kl * DFF * L;
#pragma unroll
    for (int j = 0; j < 8; ++j)
      v[j] = (lcol < L) ? src[(size_t)(db + j) * L + lcol] : 0.f;
  } else {
    const int g = gid - NW1 - NW2;
    const int kk = g / WHFRAGS, rem = g % WHFRAGS;
    const int nt = rem / (KS1 * 64), ks = (rem / 64) % KS1;
    const int o = nt * 16 + rm, lb = ks * 32 + q * 8;
    const float* src = Wh + (size_t)kk * L * O;
#pragma unroll
    for (int j = 0; j < 8; ++j) {
      const int l = lb + j;
      v[j] = (l < L) ? src[(size_t)l * O + o] : 0.f;
    }
  }
  uint4 w;
  w.x = (u32)f2bf(v[0]) | ((u32)f2bf(v[1]) << 16);
  w.y = (u32)f2bf(v[2]) | ((u32)f2bf(v[3]) << 16);
  w.z = (u32)f2bf(v[4]) | ((u32)f2bf(v[5]) << 16);
  w.w = (u32)f2bf(v[6]) | ((u32)f2bf(v[7]) << 16);
  *(uint4*)(wbuf + (size_t)gid * 8) = w;
}

__global__ __launch_bounds__(512, 2) void mlp_mfma(
    const float* __restrict__ x, const float* __restrict__ rev_w,
    const float* __restrict__ rev_b, const float* __restrict__ b1,
    const float* __restrict__ b2, const float* __restrict__ bh,
    const int* __restrict__ meta, const u16* __restrict__ wbuf,
    float* __restrict__ out) {
  __shared__ __align__(16) u16 zb[TM][ZBS];       // bf16 z (B-frag source)
  __shared__ __align__(16) char ubuf[TM * HSC * 2];  // z32 (init) / Hsh union
  __shared__ float s_mean[TM], s_std[TM], s_rw[TM], s_rb[TM];
  __shared__ int s_b[TM], s_c[TM];
  float(*z32)[Z32S] = (float(*)[Z32S])ubuf;  // 45568 B <= 66048 B
  u16(*Hsh)[HSC] = (u16(*)[HSC])ubuf;

  const int tid = threadIdx.x;
  const int wid = tid >> 6;  // 0..7
  const int lane = tid & 63;
  const int q = lane >> 4, rm = lane & 15;

  // cluster->XCD affinity: tiles are cluster-sorted; XCD (bid&7) gets a
  // contiguous 32-tile range -> per-XCD weight working set ~1 cluster.
  const int swz = (blockIdx.x & 7) * 32 + (blockIdx.x >> 3);
  const int info = meta[swz];
  const int kcl = info >> 16;
  const int rstart = info & 0xffff;
  const int cofs = meta[512 + kcl];
  const int cnt = meta[512 + kcl + 1] - cofs;

  // ---- RevIN: 32 rows, stats, write z32 (fp32) + zb (bf16) ----
  for (int i = 0; i < 4; ++i) {
    const int t = wid * 4 + i;
    const int ri = rstart + t;
    const int b = ri / cnt;
    const int c = meta[256 + cofs + (ri % cnt)];
    const float* xrow = x + (size_t)(b * C + c) * L;
    float v[6], s = 0.f, s2 = 0.f;
#pragma unroll
    for (int jj = 0; jj < 6; ++jj) {
      const int j = lane + jj * 64;
      v[jj] = (j < L) ? xrow[j] : 0.f;
      s += v[jj];
      s2 += v[jj] * v[jj];
    }
#pragma unroll
    for (int off = 32; off > 0; off >>= 1) {
      s += __shfl_down(s, off);
      s2 += __shfl_down(s2, off);
    }
    s = __shfl(s, 0);
    s2 = __shfl(s2, 0);
    const float mean = s * (1.f / L);
    const float var = s2 * (1.f / L) - mean * mean;
    const float stdv = sqrtf(var + 1e-5f);
    const float rstd = 1.f / stdv;
    const float rw = rev_w[c], rb_ = rev_b[c];
#pragma unroll
    for (int jj = 0; jj < 6; ++jj) {
      const int j = lane + jj * 64;
      if (j < L) {
        const float zn = (v[jj] - mean) * rstd * rw + rb_;
        z32[t][j] = zn;
        zb[t][j] = f2bf(zn);
      }
    }
    if (lane < LP - L) {  // zero K-pad cols 336..351
      z32[t][L + lane] = 0.f;
      zb[t][L + lane] = 0;
    }
    if (lane == 0) {
      s_mean[t] = mean;
      s_std[t] = stdv;
      s_rw[t] = rw;
      s_rb[t] = rb_;
      s_b[t] = b;
      s_c[t] = c;
    }
  }
  __syncthreads();

  // ---- fp32 residual masters -> registers (D-layout, per-wave l-tiles) ----
  f32x4 zm[3][2];
#pragma unroll
  for (int t = 0; t < 3; ++t)
#pragma unroll
    for (int rg = 0; rg < 2; ++rg) zm[t][rg] = f32x4{0.f, 0.f, 0.f, 0.f};
#pragma unroll
  for (int t = 0; t < 3; ++t) {
    const int nt2 = wid + 8 * t;
    if (nt2 < NT2) {
#pragma unroll
      for (int rg = 0; rg < 2; ++rg)
        zm[t][rg] = *(const f32x4*)&z32[rm + 16 * rg][nt2 * 16 + q * 4];
    }
  }
  __syncthreads();  // all z32 reads done before Hsh overwrites ubuf

  const u16* w1b = wbuf;
  const u16* w2b = wbuf + (size_t)NW1 * 8;
  const u16* whb = wbuf + (size_t)(NW1 + NW2) * 8;

  // ---- 2 residual MLP layers ----
  for (int l = 0; l < NL; ++l) {
    const int kl = kcl * NL + l;
    const u16* W1f = w1b + (size_t)kl * W1FRAGS * 8;
    const u16* W2f = w2b + (size_t)kl * W2FRAGS * 8;
    const float* b1p = b1 + kl * DFF;
    const float* b2p = b2 + kl * L;

    // -- phase 1: H = relu(z @ W1 + b1); wave owns 8 d-tiles, 2 groups of 4
    for (int g = 0; g < 2; ++g) {
      const int ntb = wid * 8 + g * 4;
      f32x4 acc[4][2];
#pragma unroll
      for (int t = 0; t < 4; ++t)
#pragma unroll
        for (int rg = 0; rg < 2; ++rg) acc[t][rg] = f32x4{0.f, 0.f, 0.f, 0.f};
      for (int ks = 0; ks < KS1; ++ks) {
        const bf16x8 zf0 = *(const bf16x8*)&zb[rm][ks * 32 + q * 8];
        const bf16x8 zf1 = *(const bf16x8*)&zb[rm + 16][ks * 32 + q * 8];
#pragma unroll
        for (int t = 0; t < 4; ++t) {
          const bf16x8 af = *(const bf16x8*)(
              W1f + (size_t)(ntb + t) * (KS1 * 512) + ks * 512 + lane * 8);
          acc[t][0] =
              __builtin_amdgcn_mfma_f32_16x16x32_bf16(af, zf0, acc[t][0], 0, 0, 0);
          acc[t][1] =
              __builtin_amdgcn_mfma_f32_16x16x32_bf16(af, zf1, acc[t][1], 0, 0, 0);
        }
      }
#pragma unroll
      for (int t = 0; t < 4; ++t) {
        const int nt = ntb + t;
        const float4 bq = *(const float4*)(b1p + nt * 16 + q * 4);
#pragma unroll
        for (int rg = 0; rg < 2; ++rg) {
          uint2 hw;
          hw.x = (u32)f2bf(fmaxf(acc[t][rg][0] + bq.x, 0.f)) |
                 ((u32)f2bf(fmaxf(acc[t][rg][1] + bq.y, 0.f)) << 16);
          hw.y = (u32)f2bf(fmaxf(acc[t][rg][2] + bq.z, 0.f)) |
                 ((u32)f2bf(fmaxf(acc[t][rg][3] + bq.w, 0.f)) << 16);
          *(uint2*)&Hsh[rm + 16 * rg][nt * 16 + q * 4] = hw;
        }
      }
    }
    __syncthreads();

    // -- phase 2: z += H @ W2 + b2; wave owns l-tiles wid, wid+8, wid+16
    f32x4 zacc[3][2];
#pragma unroll
    for (int t = 0; t < 3; ++t)
#pragma unroll
      for (int rg = 0; rg < 2; ++rg) zacc[t][rg] = f32x4{0.f, 0.f, 0.f, 0.f};
    for (int ks = 0; ks < KS2; ++ks) {
      const bf16x8 hf0 = *(const bf16x8*)&Hsh[rm][ks * 32 + q * 8];
      const bf16x8 hf1 = *(const bf16x8*)&Hsh[rm + 16][ks * 32 + q * 8];
#pragma unroll
      for (int t = 0; t < 3; ++t) {
        const int nt2 = wid + 8 * t;
        if (nt2 < NT2) {
          const bf16x8 af = *(const bf16x8*)(
              W2f + (size_t)nt2 * (KS2 * 512) + ks * 512 + lane * 8);
          zacc[t][0] =
              __builtin_amdgcn_mfma_f32_16x16x32_bf16(af, hf0, zacc[t][0], 0, 0, 0);
          zacc[t][1] =
              __builtin_amdgcn_mfma_f32_16x16x32_bf16(af, hf1, zacc[t][1], 0, 0, 0);
        }
      }
    }
    // z-update: masters += zacc + b2; refresh bf16 zb
#pragma unroll
    for (int t = 0; t < 3; ++t) {
      const int nt2 = wid + 8 * t;
      if (nt2 < NT2) {
        const int lc = nt2 * 16 + q * 4;
        float4 bq = make_float4(0.f, 0.f, 0.f, 0.f);
        if (lc < L) bq = *(const float4*)(b2p + lc);
#pragma unroll
        for (int rg = 0; rg < 2; ++rg) {
          zm[t][rg][0] += zacc[t][rg][0] + bq.x;
          zm[t][rg][1] += zacc[t][rg][1] + bq.y;
          zm[t][rg][2] += zacc[t][rg][2] + bq.z;
          zm[t][rg][3] += zacc[t][rg][3] + bq.w;
          uint2 zw;
          zw.x = (u32)f2bf(zm[t][rg][0]) | ((u32)f2bf(zm[t][rg][1]) << 16);
          zw.y = (u32)f2bf(zm[t][rg][2]) | ((u32)f2bf(zm[t][rg][3]) << 16);
          *(uint2*)&zb[rm + 16 * rg][lc] = zw;
        }
      }
    }
    __syncthreads();
  }

  // ---- head: y = z @ Wh + bh, denorm, scatter out[b][o][c] ----
  if (wid < NTH) {
    const u16* Whf =
        whb + (size_t)kcl * WHFRAGS * 8 + (size_t)wid * (KS1 * 512) + lane * 8;
    f32x4 acc0 = {0.f, 0.f, 0.f, 0.f}, acc1 = {0.f, 0.f, 0.f, 0.f};
    for (int ks = 0; ks < KS1; ++ks) {
      const bf16x8 af = *(const bf16x8*)(Whf + ks * 512);
      const bf16x8 zf0 = *(const bf16x8*)&zb[rm][ks * 32 + q * 8];
      const bf16x8 zf1 = *(const bf16x8*)&zb[rm + 16][ks * 32 + q * 8];
      acc0 = __builtin_amdgcn_mfma_f32_16x16x32_bf16(af, zf0, acc0, 0, 0, 0);
      acc1 = __builtin_amdgcn_mfma_f32_16x16x32_bf16(af, zf1, acc1, 0, 0, 0);
    }
    const float4 bq = *(const float4*)(bh + kcl * O + wid * 16 + q * 4);
    const float bqa[4] = {bq.x, bq.y, bq.z, bq.w};
#pragma unroll
    for (int rg = 0; rg < 2; ++rg) {
      const int row = rm + 16 * rg;
      const float mean = s_mean[row], stdv = s_std[row];
      const float rw = s_rw[row], rb_ = s_rb[row];
      const int ob = s_b[row], oc = s_c[row];
      const f32x4 acc = rg ? acc1 : acc0;
#pragma unroll
      for (int gg = 0; gg < 4; ++gg) {
        const int o = wid * 16 + q * 4 + gg;
        const float y = acc[gg] + bqa[gg];
        out[((size_t)ob * O + o) * C + oc] = (y - rb_) / rw * stdv + mean;
      }
    }
  }
}

extern "C" void kernel_launch(void* const* d_in, const int* in_sizes, int n_in,
                              void* d_out, int out_size, void* d_ws,
                              size_t ws_size, hipStream_t stream) {
  const float* x = (const float*)d_in[0];
  const float* rev_w = (const float*)d_in[1];
  const float* rev_b = (const float*)d_in[2];
  const float* W1 = (const float*)d_in[3];
  const float* b1 = (const float*)d_in[4];
  const float* W2 = (const float*)d_in[5];
  const float* b2 = (const float*)d_in[6];
  const float* Wh = (const float*)d_in[7];
  const float* bh = (const float*)d_in[8];
  const int* assign = (const int*)d_in[9];
  float* out = (float*)d_out;

  int* meta = (int*)d_ws;                  // ~2.1 KB
  u16* wbuf = (u16*)((char*)d_ws + 4096);  // 11.8 MB bf16 fragments

  build_tables<<<1, 256, 0, stream>>>(assign, meta);
  repack<<<NFRAG / 256, 256, 0, stream>>>(W1, W2, Wh, wbuf);
  mlp_mfma<<<NTILES, 512, 0, stream>>>(x, rev_w, rev_b, b1, b2, bh, meta, wbuf,
                                       out);
}

// Round 5
// 165.787 us; speedup vs baseline: 4.8793x; 1.2450x over previous
//
#include <hip/hip_runtime.h>
#include <math.h>

// TSMixerH: B=32,C=256,L=336,O=96,K=4,NL=2,DFF=1024
// Round 5: TM=32 kept (A-frag reuse x2), but restore 2 blocks/CU:
//   - H computed in two DFF-chunks of 512 -> Hsh 33KB; no z32 LDS buffer
//     (fp32 register masters init from bf16 zb; costs <=0.01 absmax)
//   - LDS ~57KB -> 2 blocks/CU, 16 waves/CU (launch_bounds(512,4))
//   - explicit a_cur/a_nxt register double-buffer for weight fragments
//   - phase-2 MFMA accumulates directly into zm masters (saves 24 VGPRs)
// r4 regression root cause: 88KB LDS -> 1 block/CU -> barrier drained the
// whole CU at every __syncthreads (no co-resident block to cover latency).

typedef unsigned short u16;
typedef unsigned int u32;
typedef unsigned long long u64;

constexpr int B = 32, C = 256, L = 336, O = 96, K = 4, NL = 2, DFF = 1024;
constexpr int TM = 32;
constexpr int NTILES = (B * C) / TM;  // 256
constexpr int LP = 352;               // L padded to mult of 32
constexpr int KS1 = LP / 32;          // 11
constexpr int KS2 = DFF / 32;         // 32
constexpr int NT2 = LP / 16;          // 22
constexpr int NTH = O / 16;           // 6
constexpr int DC = 512;               // DFF chunk
constexpr int KSC = DC / 32;          // 16 (K-steps per chunk, phase 2)
constexpr int NTC = DC / 16;          // 32 (d-tiles per chunk, phase 1)
constexpr int ZBS = 360;              // bf16 z row stride (u16)
constexpr int HSC = DC + 8;           // 520 bf16 H row stride (u16)

constexpr int W1FRAGS = (DFF / 16) * KS1 * 64;  // 45056
constexpr int W2FRAGS = NT2 * KS2 * 64;         // 45056
constexpr int WHFRAGS = NTH * KS1 * 64;         // 4224
constexpr int NW1 = W1FRAGS * K * NL;           // 360448
constexpr int NW2 = W2FRAGS * K * NL;           // 360448
constexpr int NWH = WHFRAGS * K;                // 16896
constexpr int NFRAG = NW1 + NW2 + NWH;          // 737792 = 2882*256

typedef __bf16 bf16x8 __attribute__((ext_vector_type(8)));
typedef float f32x4 __attribute__((ext_vector_type(4)));

__device__ __forceinline__ u16 f2bf(float f) {
  union { float f; u32 u; } v;
  v.f = f;
  u32 r = v.u + 0x7fffu + ((v.u >> 16) & 1u);  // RNE
  return (u16)(r >> 16);
}
__device__ __forceinline__ float bf2f(u16 h) {
  union { u32 u; float f; } v;
  v.u = ((u32)h) << 16;
  return v.f;
}

// meta layout (ints): [0..255] tiles (k<<16 | rstart), [256..511] chlist,
//                     [512..516] cofs
__global__ __launch_bounds__(256) void build_tables(
    const int* __restrict__ assign, int* __restrict__ meta) {
  __shared__ int wcnt[4][K];
  __shared__ int pre[4][K];
  __shared__ int cofs[K + 1];
  const int tid = threadIdx.x;
  const int w = tid >> 6, lane = tid & 63;
  const int a = assign[tid];
  const u64 below = (1ull << lane) - 1ull;
  int myrank = 0;
#pragma unroll
  for (int k = 0; k < K; ++k) {
    const u64 m = __ballot(a == k);
    if (a == k) myrank = (int)__popcll(m & below);
    if (lane == 0) wcnt[w][k] = (int)__popcll(m);
  }
  __syncthreads();
  if (tid == 0) {
    int tot[K];
    for (int k = 0; k < K; ++k) {
      int s = 0;
      for (int ww = 0; ww < 4; ++ww) {
        pre[ww][k] = s;
        s += wcnt[ww][k];
      }
      tot[k] = s;
    }
    cofs[0] = 0;
    for (int k = 0; k < K; ++k) cofs[k + 1] = cofs[k] + tot[k];
    for (int k = 0; k <= K; ++k) meta[512 + k] = cofs[k];
  }
  __syncthreads();
  const int pos = cofs[a] + pre[w][a] + myrank;
  meta[256 + pos] = tid;  // chlist
  int k = 0;
  while (k < K - 1 && tid >= cofs[k + 1]) ++k;
  meta[tid] = (k << 16) | ((tid - cofs[k]) * TM);
}

// Repack weights into bf16 A-fragment order.
// A-frag (16x16x32): lane holds A[m=lane&15][k=(lane>>4)*8+j], j=0..7.
__global__ __launch_bounds__(256) void repack(const float* __restrict__ W1,
                                              const float* __restrict__ W2,
                                              const float* __restrict__ Wh,
                                              u16* __restrict__ wbuf) {
  const int gid = blockIdx.x * 256 + threadIdx.x;
  const int lane = gid & 63;
  const int q = lane >> 4, rm = lane & 15;
  float v[8];
  if (gid < NW1) {
    const int kl = gid / W1FRAGS, rem = gid % W1FRAGS;
    const int nt = rem / (KS1 * 64), ks = (rem / 64) % KS1;
    const int d = nt * 16 + rm, lb = ks * 32 + q * 8;
    const float* src = W1 + (size_t)kl * L * DFF;
#pragma unroll
    for (int j = 0; j < 8; ++j) {
      const int l = lb + j;
      v[j] = (l < L) ? src[(size_t)l * DFF + d] : 0.f;
    }
  } else if (gid < NW1 + NW2) {
    const int g = gid - NW1;
    const int kl = g / W2FRAGS, rem = g % W2FRAGS;
    const int nt = rem / (KS2 * 64), ks = (rem / 64) % KS2;
    const int lcol = nt * 16 + rm, db = ks * 32 + q * 8;
    const float* src = W2 + (size_t)kl * DFF * L;
#pragma unroll
    for (int j = 0; j < 8; ++j)
      v[j] = (lcol < L) ? src[(size_t)(db + j) * L + lcol] : 0.f;
  } else {
    const int g = gid - NW1 - NW2;
    const int kk = g / WHFRAGS, rem = g % WHFRAGS;
    const int nt = rem / (KS1 * 64), ks = (rem / 64) % KS1;
    const int o = nt * 16 + rm, lb = ks * 32 + q * 8;
    const float* src = Wh + (size_t)kk * L * O;
#pragma unroll
    for (int j = 0; j < 8; ++j) {
      const int l = lb + j;
      v[j] = (l < L) ? src[(size_t)l * O + o] : 0.f;
    }
  }
  uint4 w;
  w.x = (u32)f2bf(v[0]) | ((u32)f2bf(v[1]) << 16);
  w.y = (u32)f2bf(v[2]) | ((u32)f2bf(v[3]) << 16);
  w.z = (u32)f2bf(v[4]) | ((u32)f2bf(v[5]) << 16);
  w.w = (u32)f2bf(v[6]) | ((u32)f2bf(v[7]) << 16);
  *(uint4*)(wbuf + (size_t)gid * 8) = w;
}

__global__ __launch_bounds__(512, 4) void mlp_mfma(
    const float* __restrict__ x, const float* __restrict__ rev_w,
    const float* __restrict__ rev_b, const float* __restrict__ b1,
    const float* __restrict__ b2, const float* __restrict__ bh,
    const int* __restrict__ meta, const u16* __restrict__ wbuf,
    float* __restrict__ out) {
  __shared__ __align__(16) u16 zb[TM][ZBS];   // bf16 z  (23.0 KB)
  __shared__ __align__(16) u16 Hsh[TM][HSC];  // bf16 H chunk (33.3 KB)
  __shared__ float s_mean[TM], s_std[TM], s_rw[TM], s_rb[TM];
  __shared__ int s_b[TM], s_c[TM];

  const int tid = threadIdx.x;
  const int wid = tid >> 6;  // 0..7
  const int lane = tid & 63;
  const int q = lane >> 4, rm = lane & 15;

  // cluster->XCD affinity: tiles are cluster-sorted; XCD (bid&7) gets a
  // contiguous 32-tile range -> per-XCD weight working set ~1 cluster.
  const int swz = (blockIdx.x & 7) * 32 + (blockIdx.x >> 3);
  const int info = meta[swz];
  const int kcl = info >> 16;
  const int rstart = info & 0xffff;
  const int cofs = meta[512 + kcl];
  const int cnt = meta[512 + kcl + 1] - cofs;

  // ---- RevIN: 32 rows, stats, write zb (bf16, K-pad zeroed) ----
  for (int i = 0; i < 4; ++i) {
    const int t = wid * 4 + i;
    const int ri = rstart + t;
    const int b = ri / cnt;
    const int c = meta[256 + cofs + (ri % cnt)];
    const float* xrow = x + (size_t)(b * C + c) * L;
    float v[6], s = 0.f, s2 = 0.f;
#pragma unroll
    for (int jj = 0; jj < 6; ++jj) {
      const int j = lane + jj * 64;
      v[jj] = (j < L) ? xrow[j] : 0.f;
      s += v[jj];
      s2 += v[jj] * v[jj];
    }
#pragma unroll
    for (int off = 32; off > 0; off >>= 1) {
      s += __shfl_down(s, off);
      s2 += __shfl_down(s2, off);
    }
    s = __shfl(s, 0);
    s2 = __shfl(s2, 0);
    const float mean = s * (1.f / L);
    const float var = s2 * (1.f / L) - mean * mean;
    const float stdv = sqrtf(var + 1e-5f);
    const float rstd = 1.f / stdv;
    const float rw = rev_w[c], rb_ = rev_b[c];
#pragma unroll
    for (int jj = 0; jj < 6; ++jj) {
      const int j = lane + jj * 64;
      if (j < L) zb[t][j] = f2bf((v[jj] - mean) * rstd * rw + rb_);
    }
    if (lane < LP - L) zb[t][L + lane] = 0;  // zero K-pad cols 336..351
    if (lane == 0) {
      s_mean[t] = mean;
      s_std[t] = stdv;
      s_rw[t] = rw;
      s_rb[t] = rb_;
      s_b[t] = b;
      s_c[t] = c;
    }
  }
  __syncthreads();

  // ---- fp32 residual masters (D-layout): zm[t][rg] for l-tile wid+8t ----
  f32x4 zm[3][2];
#pragma unroll
  for (int t = 0; t < 3; ++t) {
    const int nt2 = wid + 8 * t;
#pragma unroll
    for (int rg = 0; rg < 2; ++rg) {
      if (nt2 < NT2) {
        const uint2 zw = *(const uint2*)&zb[rm + 16 * rg][nt2 * 16 + q * 4];
        zm[t][rg] = f32x4{bf2f((u16)zw.x), bf2f((u16)(zw.x >> 16)),
                          bf2f((u16)zw.y), bf2f((u16)(zw.y >> 16))};
      } else {
        zm[t][rg] = f32x4{0.f, 0.f, 0.f, 0.f};
      }
    }
  }

  const u16* w1b = wbuf;
  const u16* w2b = wbuf + (size_t)NW1 * 8;
  const u16* whb = wbuf + (size_t)(NW1 + NW2) * 8;

  // ---- 2 residual MLP layers, H in two DFF-chunks of 512 ----
  for (int l = 0; l < NL; ++l) {
    const int kl = kcl * NL + l;
    const u16* W1f = w1b + (size_t)kl * W1FRAGS * 8;
    const u16* W2f = w2b + (size_t)kl * W2FRAGS * 8;
    const float* b1p = b1 + kl * DFF;
    const float* b2p = b2 + kl * L;

    for (int cch = 0; cch < 2; ++cch) {
      // -- phase 1: H_chunk = relu(z @ W1 + b1); wave owns 4 d-tiles
      {
        const u16* base =
            W1f + ((size_t)(cch * NTC + wid * 4) * (KS1 * 512) + lane * 8);
        bf16x8 a_cur[4], a_nxt[4];
#pragma unroll
        for (int t = 0; t < 4; ++t)
          a_cur[t] = *(const bf16x8*)(base + (size_t)t * (KS1 * 512));
        f32x4 acc[4][2];
#pragma unroll
        for (int t = 0; t < 4; ++t)
#pragma unroll
          for (int rg = 0; rg < 2; ++rg) acc[t][rg] = f32x4{0.f, 0.f, 0.f, 0.f};
#pragma unroll 1
        for (int ks = 0; ks < KS1; ++ks) {
          if (ks + 1 < KS1) {
#pragma unroll
            for (int t = 0; t < 4; ++t)
              a_nxt[t] = *(const bf16x8*)(base + (size_t)t * (KS1 * 512) +
                                          (ks + 1) * 512);
          }
          const bf16x8 zf0 = *(const bf16x8*)&zb[rm][ks * 32 + q * 8];
          const bf16x8 zf1 = *(const bf16x8*)&zb[rm + 16][ks * 32 + q * 8];
#pragma unroll
          for (int t = 0; t < 4; ++t) {
            acc[t][0] = __builtin_amdgcn_mfma_f32_16x16x32_bf16(a_cur[t], zf0,
                                                                acc[t][0], 0, 0, 0);
            acc[t][1] = __builtin_amdgcn_mfma_f32_16x16x32_bf16(a_cur[t], zf1,
                                                                acc[t][1], 0, 0, 0);
          }
#pragma unroll
          for (int t = 0; t < 4; ++t) a_cur[t] = a_nxt[t];
        }
#pragma unroll
        for (int t = 0; t < 4; ++t) {
          const int ntl = wid * 4 + t;  // local d-tile within chunk
          const float4 bq =
              *(const float4*)(b1p + cch * DC + ntl * 16 + q * 4);
#pragma unroll
          for (int rg = 0; rg < 2; ++rg) {
            uint2 hw;
            hw.x = (u32)f2bf(fmaxf(acc[t][rg][0] + bq.x, 0.f)) |
                   ((u32)f2bf(fmaxf(acc[t][rg][1] + bq.y, 0.f)) << 16);
            hw.y = (u32)f2bf(fmaxf(acc[t][rg][2] + bq.z, 0.f)) |
                   ((u32)f2bf(fmaxf(acc[t][rg][3] + bq.w, 0.f)) << 16);
            *(uint2*)&Hsh[rm + 16 * rg][ntl * 16 + q * 4] = hw;
          }
        }
      }
      __syncthreads();

      // -- phase 2: zm += H_chunk @ W2[chunk rows]; accumulate into masters
      {
        const u16* b2base = W2f + ((size_t)(cch * KSC) * 512 + lane * 8);
        bf16x8 w_cur[3], w_nxt[3];
#pragma unroll
        for (int t = 0; t < 3; ++t) {
          const int nt2 = wid + 8 * t;
          if (nt2 < NT2)
            w_cur[t] = *(const bf16x8*)(b2base + (size_t)nt2 * (KS2 * 512));
        }
#pragma unroll 1
        for (int ks = 0; ks < KSC; ++ks) {
          if (ks + 1 < KSC) {
#pragma unroll
            for (int t = 0; t < 3; ++t) {
              const int nt2 = wid + 8 * t;
              if (nt2 < NT2)
                w_nxt[t] = *(const bf16x8*)(b2base + (size_t)nt2 * (KS2 * 512) +
                                            (ks + 1) * 512);
            }
          }
          const bf16x8 hf0 = *(const bf16x8*)&Hsh[rm][ks * 32 + q * 8];
          const bf16x8 hf1 = *(const bf16x8*)&Hsh[rm + 16][ks * 32 + q * 8];
#pragma unroll
          for (int t = 0; t < 3; ++t) {
            if (wid + 8 * t < NT2) {
              zm[t][0] = __builtin_amdgcn_mfma_f32_16x16x32_bf16(w_cur[t], hf0,
                                                                 zm[t][0], 0, 0, 0);
              zm[t][1] = __builtin_amdgcn_mfma_f32_16x16x32_bf16(w_cur[t], hf1,
                                                                 zm[t][1], 0, 0, 0);
            }
          }
#pragma unroll
          for (int t = 0; t < 3; ++t) w_cur[t] = w_nxt[t];
        }
      }
      __syncthreads();  // Hsh consumed before next chunk's phase 1 rewrites
    }

    // -- layer epilogue: zm += b2, refresh bf16 zb
#pragma unroll
    for (int t = 0; t < 3; ++t) {
      const int nt2 = wid + 8 * t;
      if (nt2 < NT2) {
        const int lc = nt2 * 16 + q * 4;
        if (lc < L) {
          const float4 bq = *(const float4*)(b2p + lc);
          zm[t][0][0] += bq.x; zm[t][0][1] += bq.y;
          zm[t][0][2] += bq.z; zm[t][0][3] += bq.w;
          zm[t][1][0] += bq.x; zm[t][1][1] += bq.y;
          zm[t][1][2] += bq.z; zm[t][1][3] += bq.w;
        }
#pragma unroll
        for (int rg = 0; rg < 2; ++rg) {
          uint2 zw;
          zw.x = (u32)f2bf(zm[t][rg][0]) | ((u32)f2bf(zm[t][rg][1]) << 16);
          zw.y = (u32)f2bf(zm[t][rg][2]) | ((u32)f2bf(zm[t][rg][3]) << 16);
          *(uint2*)&zb[rm + 16 * rg][lc] = zw;
        }
      }
    }
    __syncthreads();
  }

  // ---- head: y = z @ Wh + bh, denorm, scatter out[b][o][c] ----
  if (wid < NTH) {
    const u16* Whf =
        whb + (size_t)kcl * WHFRAGS * 8 + (size_t)wid * (KS1 * 512) + lane * 8;
    f32x4 acc0 = {0.f, 0.f, 0.f, 0.f}, acc1 = {0.f, 0.f, 0.f, 0.f};
    for (int ks = 0; ks < KS1; ++ks) {
      const bf16x8 af = *(const bf16x8*)(Whf + ks * 512);
      const bf16x8 zf0 = *(const bf16x8*)&zb[rm][ks * 32 + q * 8];
      const bf16x8 zf1 = *(const bf16x8*)&zb[rm + 16][ks * 32 + q * 8];
      acc0 = __builtin_amdgcn_mfma_f32_16x16x32_bf16(af, zf0, acc0, 0, 0, 0);
      acc1 = __builtin_amdgcn_mfma_f32_16x16x32_bf16(af, zf1, acc1, 0, 0, 0);
    }
    const float4 bq = *(const float4*)(bh + kcl * O + wid * 16 + q * 4);
    const float bqa[4] = {bq.x, bq.y, bq.z, bq.w};
#pragma unroll
    for (int rg = 0; rg < 2; ++rg) {
      const int row = rm + 16 * rg;
      const float mean = s_mean[row], stdv = s_std[row];
      const float rw = s_rw[row], rb_ = s_rb[row];
      const int ob = s_b[row], oc = s_c[row];
      const f32x4 acc = rg ? acc1 : acc0;
#pragma unroll
      for (int gg = 0; gg < 4; ++gg) {
        const int o = wid * 16 + q * 4 + gg;
        const float y = acc[gg] + bqa[gg];
        out[((size_t)ob * O + o) * C + oc] = (y - rb_) / rw * stdv + mean;
      }
    }
  }
}

extern "C" void kernel_launch(void* const* d_in, const int* in_sizes, int n_in,
                              void* d_out, int out_size, void* d_ws,
                              size_t ws_size, hipStream_t stream) {
  const float* x = (const float*)d_in[0];
  const float* rev_w = (const float*)d_in[1];
  const float* rev_b = (const float*)d_in[2];
  const float* W1 = (const float*)d_in[3];
  const float* b1 = (const float*)d_in[4];
  const float* W2 = (const float*)d_in[5];
  const float* b2 = (const float*)d_in[6];
  const float* Wh = (const float*)d_in[7];
  const float* bh = (const float*)d_in[8];
  const int* assign = (const int*)d_in[9];
  float* out = (float*)d_out;

  int* meta = (int*)d_ws;                  // ~2.1 KB
  u16* wbuf = (u16*)((char*)d_ws + 4096);  // 11.8 MB bf16 fragments

  build_tables<<<1, 256, 0, stream>>>(assign, meta);
  repack<<<NFRAG / 256, 256, 0, stream>>>(W1, W2, Wh, wbuf);
  mlp_mfma<<<NTILES, 512, 0, stream>>>(x, rev_w, rev_b, b1, b2, bh, meta, wbuf,
                                       out);
}